// Round 4
// baseline (1255.894 us; speedup 1.0000x reference)
//
#include <hip/hip_runtime.h>
#include <hip/hip_bf16.h>
#include <math.h>

#define HEADS 8
#define DH 32
#define BATCH 8
#define CDIM 512
#define NSEQ 8192
#define HID 256
#define O3 768
#define LNEPS 1e-5f
#define QSCALE 0.1767766952966369f  // 32^-0.5

typedef __bf16 bf16x8 __attribute__((ext_vector_type(8)));
typedef float f32x4 __attribute__((ext_vector_type(4)));

// dual-dtype element load: mode==1 -> fp32 buffer, mode==0 -> bf16 buffer
__device__ __forceinline__ float ldx(const void* p, size_t i, bool f32) {
  if (f32) {
    float v = ((const float*)p)[i];
    return __builtin_isfinite(v) ? v : 0.f;
  }
  return __bfloat162float(((const __hip_bfloat16*)p)[i]);
}

// stage 8 contiguous elements into LDS as bf16
__device__ __forceinline__ void stage8(__hip_bfloat16* dst, const void* src, size_t idx, bool f32) {
  if (f32) {
    const float* s = (const float*)src + idx;
#pragma unroll
    for (int t = 0; t < 8; ++t) {
      float v = s[t];
      if (!__builtin_isfinite(v)) v = 0.f;
      dst[t] = __float2bfloat16(v);
    }
  } else {
    *(int4*)dst = *(const int4*)((const __hip_bfloat16*)src + idx);
  }
}

// dual-dtype store with finite scrub (diagnostic: output can never be NaN/inf)
__device__ __forceinline__ void stx(void* p, size_t i, bool f32, float v) {
  if (!__builtin_isfinite(v)) v = 0.f;
  if (f32) ((float*)p)[i] = v;
  else ((__hip_bfloat16*)p)[i] = __float2bfloat16(v);
}

// ---------------- kernel 0: dtype detector ----------------
__global__ __launch_bounds__(256) void detect_kernel(const void* __restrict__ x, int* __restrict__ mode) {
  __shared__ int cnt;
  if (threadIdx.x == 0) cnt = 0;
  __syncthreads();
  const __hip_bfloat16* p = (const __hip_bfloat16*)x;
  int c = 0;
  for (int i = threadIdx.x; i < 4096; i += 256) {
    float v = __bfloat162float(p[i]);
    if (!(v > -1.0e3f && v < 1.0e3f)) c++;  // counts NaN too (compare is false)
  }
  atomicAdd(&cnt, c);
  __syncthreads();
  if (threadIdx.x == 0) mode[0] = (cnt > 64) ? 1 : 0;
}

// ---------------- kernel 1: LayerNorm stats (mean, rstd per (b,n)) ----------------
__global__ __launch_bounds__(256) void ln_stats_kernel(
    const void* __restrict__ x, const int* __restrict__ mode,
    float* __restrict__ mean, float* __restrict__ rstd) {
  const bool f32 = mode[0] != 0;
  int b = blockIdx.y;
  int nl = threadIdx.x & 63;
  int cp = threadIdx.x >> 6;
  int n = blockIdx.x * 64 + nl;
  size_t base = (size_t)b * CDIM * NSEQ + n;
  float s = 0.f, ss = 0.f;
  for (int c = cp * 128; c < cp * 128 + 128; ++c) {
    float v = ldx(x, base + (size_t)c * NSEQ, f32);
    s += v; ss += v * v;
  }
  __shared__ float sb[4][64], sb2[4][64];
  sb[cp][nl] = s; sb2[cp][nl] = ss;
  __syncthreads();
  if (cp == 0) {
    s = sb[0][nl] + sb[1][nl] + sb[2][nl] + sb[3][nl];
    ss = sb2[0][nl] + sb2[1][nl] + sb2[2][nl] + sb2[3][nl];
    float m = s * (1.f / CDIM);
    float var = ss * (1.f / CDIM) - m * m;
    mean[b * NSEQ + n] = m;
    rstd[b * NSEQ + n] = rsqrtf(fmaxf(var, 0.f) + LNEPS);
  }
}

// ---------------- kernel 2: fused K/V GEMM + exp + context accumulation ----------------
__global__ __launch_bounds__(256) void kvctx_kernel(
    const void* __restrict__ x, const void* __restrict__ g,
    const void* __restrict__ bln, const void* __restrict__ wqkv,
    const int* __restrict__ mode,
    const float* __restrict__ mean, const float* __restrict__ rstd,
    float* __restrict__ ctxb, float* __restrict__ sumexp) {
  const bool f32 = mode[0] != 0;
  const int b = blockIdx.z;
  const int p = blockIdx.y;
  const int n0 = blockIdx.x * 128;
  __shared__ __align__(16) __hip_bfloat16 As[128 * 32];
  __shared__ __align__(16) __hip_bfloat16 Bs[128 * 40];
  __shared__ __align__(16) __hip_bfloat16 Ct[128 * 136];
  const int tid = threadIdx.x;
  const int lane = tid & 63;
  const int wv = tid >> 6;
  const int wm = wv >> 1, wn = wv & 1;
  const int quad = lane >> 4, l = lane & 15;
  f32x4 acc[4][4] = {};
  const int nn = tid & 127;
  const int cb = tid >> 7;
  const float mn = mean[b * NSEQ + n0 + nn];
  const float rs = rstd[b * NSEQ + n0 + nn];
  const size_t xbase = (size_t)b * CDIM * NSEQ + n0 + nn;
  for (int k0 = 0; k0 < CDIM; k0 += 32) {
#pragma unroll
    for (int r = 0; r < 2; ++r) {
      int idx = (r * 256 + tid) * 8;
      int row = idx >> 5, col = idx & 31;
      int srow = (row < 64) ? (256 + p * 64 + row) : (512 + p * 64 + row - 64);
      stage8(&As[idx], wqkv, (size_t)srow * CDIM + k0 + col, f32);
    }
#pragma unroll
    for (int r = 0; r < 16; ++r) {
      int c = r * 2 + cb;
      float xv = ldx(x, xbase + (size_t)(k0 + c) * NSEQ, f32);
      float xn = (xv - mn) * rs;
      xn = xn * ldx(g, k0 + c, f32) + ldx(bln, k0 + c, f32);
      Bs[nn * 40 + c] = __float2bfloat16(xn);
    }
    __syncthreads();
    bf16x8 af[4], bfr[4];
#pragma unroll
    for (int i = 0; i < 4; ++i)
      af[i] = *(const bf16x8*)&As[(wm * 64 + i * 16 + l) * 32 + quad * 8];
#pragma unroll
    for (int j = 0; j < 4; ++j)
      bfr[j] = *(const bf16x8*)&Bs[(wn * 64 + j * 16 + l) * 40 + quad * 8];
#pragma unroll
    for (int i = 0; i < 4; ++i)
#pragma unroll
      for (int j = 0; j < 4; ++j)
        acc[i][j] = __builtin_amdgcn_mfma_f32_16x16x32_bf16(af[i], bfr[j], acc[i][j], 0, 0, 0);
    __syncthreads();
  }
  // epilogue: exp on K half (rows 0..63), clamp V half; write C tile to LDS
#pragma unroll
  for (int i = 0; i < 4; ++i) {
    int row = wm * 64 + i * 16 + quad * 4;
#pragma unroll
    for (int j = 0; j < 4; ++j) {
      int col = wn * 64 + j * 16 + l;
#pragma unroll
      for (int r = 0; r < 4; ++r) {
        float v = acc[i][j][r];
        if (wm == 0) v = expf(fminf(v, 20.f));
        else         v = fminf(fmaxf(v, -1.0e4f), 1.0e4f);
        Ct[(row + r) * 136 + col] = __float2bfloat16(v);
      }
    }
  }
  __syncthreads();
  const int mi = wm, ni = wn;
#pragma unroll
  for (int hh = 0; hh < 2; ++hh) {
    f32x4 ca = {};
#pragma unroll
    for (int ks = 0; ks < 4; ++ks) {
      bf16x8 ea = *(const bf16x8*)&Ct[(hh * 32 + mi * 16 + l) * 136 + ks * 32 + quad * 8];
      bf16x8 vb = *(const bf16x8*)&Ct[(64 + hh * 32 + ni * 16 + l) * 136 + ks * 32 + quad * 8];
      ca = __builtin_amdgcn_mfma_f32_16x16x32_bf16(ea, vb, ca, 0, 0, 0);
    }
    int h = p * 2 + hh;
    float* cp = ctxb + (size_t)(b * HEADS + h) * DH * DH;
#pragma unroll
    for (int r = 0; r < 4; ++r)
      atomicAdd(&cp[(mi * 16 + quad * 4 + r) * DH + ni * 16 + l], ca[r]);
  }
  if (tid < 64) {
    int hh = tid >> 5, d = tid & 31;
    float s = 0.f;
#pragma unroll 16
    for (int c = 0; c < 128; ++c) s += __bfloat162float(Ct[tid * 136 + c]);
    atomicAdd(&sumexp[(b * HEADS + p * 2 + hh) * DH + d], s);
  }
}

// ---------------- kernel 3: W2 build (clamped) ----------------
__global__ __launch_bounds__(256) void w2_build_kernel(
    const void* __restrict__ wout, const int* __restrict__ mode,
    const float* __restrict__ ctxb, const float* __restrict__ sumexp,
    __hip_bfloat16* __restrict__ w2) {
  const bool f32 = mode[0] != 0;
  const int o = blockIdx.x;
  const int b = blockIdx.y;
  const int hd = threadIdx.x;
  const int h = hd >> 5, d = hd & 31;
  const float* cp = ctxb + ((size_t)(b * HEADS + h) * DH + d) * DH;
  float a = 0.f;
#pragma unroll
  for (int e = 0; e < DH; ++e) a += ldx(wout, (size_t)o * HID + h * DH + e, f32) * cp[e];
  float se = fmaxf(sumexp[(b * HEADS + h) * DH + d], 1e-30f);
  float v = a * QSCALE / se;
  v = fminf(fmaxf(v, -1.0e3f), 1.0e3f);  // kill inf -> no inf*0 NaN downstream
  w2[((size_t)b * CDIM + o) * HID + hd] = __float2bfloat16(v);
}

// ---------------- kernel 4: W3[b] = W2[b] (512x256) * Wq (256x512) ----------------
__global__ __launch_bounds__(256) void w3_gemm_kernel(
    const __hip_bfloat16* __restrict__ w2, const void* __restrict__ wqkv,
    const int* __restrict__ mode, __hip_bfloat16* __restrict__ w3) {
  const bool f32 = mode[0] != 0;
  const int b = blockIdx.z;
  const int m0 = blockIdx.y * 128;
  const int n0 = blockIdx.x * 128;
  __shared__ __align__(16) __hip_bfloat16 As[128 * 32];
  __shared__ __align__(16) __hip_bfloat16 Bs[128 * 40];
  const int tid = threadIdx.x;
  const int lane = tid & 63;
  const int wv = tid >> 6;
  const int wm = wv >> 1, wn = wv & 1;
  const int quad = lane >> 4, l = lane & 15;
  f32x4 acc[4][4] = {};
  const int nn = tid & 127;
  const int cb = tid >> 7;
  const __hip_bfloat16* wa = w2 + (size_t)b * CDIM * HID;
  for (int k0 = 0; k0 < HID; k0 += 32) {
#pragma unroll
    for (int r = 0; r < 2; ++r) {
      int idx = (r * 256 + tid) * 8;
      int row = idx >> 5, col = idx & 31;
      *(int4*)&As[idx] = *(const int4*)&wa[(size_t)(m0 + row) * HID + k0 + col];
    }
#pragma unroll
    for (int r = 0; r < 16; ++r) {
      int hdl = r * 2 + cb;
      Bs[nn * 40 + hdl] = __float2bfloat16(ldx(wqkv, (size_t)(k0 + hdl) * CDIM + n0 + nn, f32));
    }
    __syncthreads();
    bf16x8 af[4], bfr[4];
#pragma unroll
    for (int i = 0; i < 4; ++i)
      af[i] = *(const bf16x8*)&As[(wm * 64 + i * 16 + l) * 32 + quad * 8];
#pragma unroll
    for (int j = 0; j < 4; ++j)
      bfr[j] = *(const bf16x8*)&Bs[(wn * 64 + j * 16 + l) * 40 + quad * 8];
#pragma unroll
    for (int i = 0; i < 4; ++i)
#pragma unroll
      for (int j = 0; j < 4; ++j)
        acc[i][j] = __builtin_amdgcn_mfma_f32_16x16x32_bf16(af[i], bfr[j], acc[i][j], 0, 0, 0);
    __syncthreads();
  }
#pragma unroll
  for (int i = 0; i < 4; ++i) {
    int orow = m0 + wm * 64 + i * 16 + quad * 4;
#pragma unroll
    for (int j = 0; j < 4; ++j) {
      int ncol = n0 + wn * 64 + j * 16 + l;
      __hip_bfloat16* op = w3 + ((size_t)b * CDIM + orow) * CDIM + ncol;
#pragma unroll
      for (int r = 0; r < 4; ++r) {
        float v = fminf(fmaxf(acc[i][j][r], -1.0e4f), 1.0e4f);
        op[(size_t)r * CDIM] = __float2bfloat16(v);
      }
    }
  }
}

// ---------------- kernel 5: out = W3[b] * xnorm + b_out + x ----------------
__global__ __launch_bounds__(256) void out_gemm_kernel(
    const void* __restrict__ x, const void* __restrict__ g,
    const void* __restrict__ bln, const __hip_bfloat16* __restrict__ w3,
    const int* __restrict__ mode,
    const float* __restrict__ mean, const float* __restrict__ rstd,
    const void* __restrict__ bout, void* __restrict__ out) {
  const bool f32 = mode[0] != 0;
  const int b = blockIdx.z;
  const int m0 = blockIdx.y * 128;
  const int n0 = blockIdx.x * 128;
  __shared__ __align__(16) __hip_bfloat16 As[128 * 32];
  __shared__ __align__(16) __hip_bfloat16 Bs[128 * 40];
  const int tid = threadIdx.x;
  const int lane = tid & 63;
  const int wv = tid >> 6;
  const int wm = wv >> 1, wn = wv & 1;
  const int quad = lane >> 4, l = lane & 15;
  f32x4 acc[4][4] = {};
  const int nn = tid & 127;
  const int cb = tid >> 7;
  const float mn = mean[b * NSEQ + n0 + nn];
  const float rs = rstd[b * NSEQ + n0 + nn];
  const size_t xbase = (size_t)b * CDIM * NSEQ + n0 + nn;
  const __hip_bfloat16* wa = w3 + (size_t)b * CDIM * CDIM;
  for (int k0 = 0; k0 < CDIM; k0 += 32) {
#pragma unroll
    for (int r = 0; r < 2; ++r) {
      int idx = (r * 256 + tid) * 8;
      int row = idx >> 5, col = idx & 31;
      *(int4*)&As[idx] = *(const int4*)&wa[(size_t)(m0 + row) * CDIM + k0 + col];
    }
#pragma unroll
    for (int r = 0; r < 16; ++r) {
      int c = r * 2 + cb;
      float xv = ldx(x, xbase + (size_t)(k0 + c) * NSEQ, f32);
      float xn = (xv - mn) * rs;
      xn = xn * ldx(g, k0 + c, f32) + ldx(bln, k0 + c, f32);
      Bs[nn * 40 + c] = __float2bfloat16(xn);
    }
    __syncthreads();
    bf16x8 af[4], bfr[4];
#pragma unroll
    for (int i = 0; i < 4; ++i)
      af[i] = *(const bf16x8*)&As[(wm * 64 + i * 16 + l) * 32 + quad * 8];
#pragma unroll
    for (int j = 0; j < 4; ++j)
      bfr[j] = *(const bf16x8*)&Bs[(wn * 64 + j * 16 + l) * 40 + quad * 8];
#pragma unroll
    for (int i = 0; i < 4; ++i)
#pragma unroll
      for (int j = 0; j < 4; ++j)
        acc[i][j] = __builtin_amdgcn_mfma_f32_16x16x32_bf16(af[i], bfr[j], acc[i][j], 0, 0, 0);
    __syncthreads();
  }
#pragma unroll
  for (int i = 0; i < 4; ++i) {
    int orow = m0 + wm * 64 + i * 16 + quad * 4;
#pragma unroll
    for (int j = 0; j < 4; ++j) {
      int ncol = n0 + wn * 64 + j * 16 + l;
#pragma unroll
      for (int r = 0; r < 4; ++r) {
        size_t oi = ((size_t)b * CDIM + orow + r) * NSEQ + ncol;
        float v = acc[i][j][r] + ldx(bout, orow + r, f32) + ldx(x, oi, f32);
        stx(out, oi, f32, v);
      }
    }
  }
}

extern "C" void kernel_launch(void* const* d_in, const int* in_sizes, int n_in,
                              void* d_out, int out_size, void* d_ws, size_t ws_size,
                              hipStream_t stream) {
  (void)in_sizes; (void)n_in; (void)out_size; (void)ws_size;
  const void* x    = d_in[0];
  const void* g    = d_in[1];
  const void* bln  = d_in[2];
  const void* wqkv = d_in[3];
  const void* wout = d_in[4];
  const void* bout = d_in[5];

  // workspace layout (~7 MB total)
  float* mean   = (float*)d_ws;                    // 8*8192
  float* rstd   = mean + BATCH * NSEQ;             // 8*8192
  float* ctxb   = rstd + BATCH * NSEQ;             // 65536
  float* sumexp = ctxb + BATCH * HEADS * DH * DH;  // 2048
  int*   mode   = (int*)(sumexp + BATCH * HEADS * DH);
  __hip_bfloat16* w2 = (__hip_bfloat16*)(mode + 64);            // 8*512*256
  __hip_bfloat16* w3 = w2 + (size_t)BATCH * CDIM * HID;         // 8*512*512

  hipMemsetAsync(ctxb, 0, (BATCH * HEADS * DH * DH + BATCH * HEADS * DH) * sizeof(float), stream);

  detect_kernel<<<1, 256, 0, stream>>>(x, mode);
  ln_stats_kernel<<<dim3(NSEQ / 64, BATCH), 256, 0, stream>>>(x, mode, mean, rstd);
  kvctx_kernel<<<dim3(NSEQ / 128, HEADS / 2, BATCH), 256, 0, stream>>>(
      x, g, bln, wqkv, mode, mean, rstd, ctxb, sumexp);
  w2_build_kernel<<<dim3(CDIM, BATCH), 256, 0, stream>>>(wout, mode, ctxb, sumexp, w2);
  w3_gemm_kernel<<<dim3(CDIM / 128, CDIM / 128, BATCH), 256, 0, stream>>>(w2, wqkv, mode, w3);
  out_gemm_kernel<<<dim3(NSEQ / 128, CDIM / 128, BATCH), 256, 0, stream>>>(
      x, g, bln, w3, mode, mean, rstd, bout, d_out);
}